// Round 1
// baseline (486.499 us; speedup 1.0000x reference)
//
#include <hip/hip_runtime.h>
#include <stdint.h>

#define NSEG 65536
#define D 64

// Monotone order-preserving float->uint encoding: for floats a<b  =>  enc(a)<enc(b) (unsigned).
__device__ __forceinline__ unsigned enc_f32(float f) {
    unsigned b = __float_as_uint(f);
    return (b & 0x80000000u) ? ~b : (b | 0x80000000u);
}
__device__ __forceinline__ float dec_f32(unsigned m) {
    unsigned b = (m & 0x80000000u) ? (m & 0x7FFFFFFFu) : ~m;
    return __uint_as_float(b);
}

// Each block = 256 threads = 4 waves. Each wave owns 64 consecutive rows.
// Within a wave: lanes are split 16 lanes/row over 4 rows per float4-load
// iteration (lane reads cols [(lane&15)*4, +4) of row rowStart+it*4+(lane>>4)).
// Each lane run-length-groups its own (sorted) row subsequence and flushes a
// per-segment running max with atomicMax on the encoded output.
__global__ __launch_bounds__(256) void segmax_kernel(const float* __restrict__ x,
                                                     const int* __restrict__ index,
                                                     unsigned* __restrict__ out_enc) {
    const int lane = threadIdx.x & 63;
    const int wave = threadIdx.x >> 6;
    const int rowStart = (blockIdx.x * 4 + wave) * 64;

    // Coalesced preload of this wave's 64 index values; distribute via shfl.
    const int idx_lane = index[rowStart + lane];

    const int sub  = lane >> 4;        // which of the 4 rows in each iteration
    const int col4 = (lane & 15) * 4;  // starting column of this lane's float4

    int cur;
    float4 m;
    {
        cur = __shfl(idx_lane, sub);
        m = *reinterpret_cast<const float4*>(x + (size_t)(rowStart + sub) * D + col4);
    }
#pragma unroll
    for (int it = 1; it < 16; ++it) {
        const int r   = it * 4 + sub;
        const int seg = __shfl(idx_lane, r);
        const float4 v = *reinterpret_cast<const float4*>(x + (size_t)(rowStart + r) * D + col4);
        if (seg != cur) {
            unsigned* p = out_enc + (size_t)cur * D + col4;
            atomicMax(p + 0, enc_f32(m.x));
            atomicMax(p + 1, enc_f32(m.y));
            atomicMax(p + 2, enc_f32(m.z));
            atomicMax(p + 3, enc_f32(m.w));
            cur = seg;
            m = v;
        } else {
            m.x = fmaxf(m.x, v.x);
            m.y = fmaxf(m.y, v.y);
            m.z = fmaxf(m.z, v.z);
            m.w = fmaxf(m.w, v.w);
        }
    }
    {
        unsigned* p = out_enc + (size_t)cur * D + col4;
        atomicMax(p + 0, enc_f32(m.x));
        atomicMax(p + 1, enc_f32(m.y));
        atomicMax(p + 2, enc_f32(m.z));
        atomicMax(p + 3, enc_f32(m.w));
    }
}

// Decode in place. Sentinel 0 (no row touched the segment) -> 0.0f, matching
// torch_scatter's zero-initialized output for empty segments.
__global__ __launch_bounds__(256) void finalize_kernel(unsigned* __restrict__ io, int n4) {
    const int i = blockIdx.x * 256 + threadIdx.x;
    if (i >= n4) return;
    uint4 u = reinterpret_cast<uint4*>(io)[i];
    float4 f;
    f.x = (u.x == 0u) ? 0.0f : dec_f32(u.x);
    f.y = (u.y == 0u) ? 0.0f : dec_f32(u.y);
    f.z = (u.z == 0u) ? 0.0f : dec_f32(u.z);
    f.w = (u.w == 0u) ? 0.0f : dec_f32(u.w);
    reinterpret_cast<float4*>(io)[i] = f;
}

extern "C" void kernel_launch(void* const* d_in, const int* in_sizes, int n_in,
                              void* d_out, int out_size, void* d_ws, size_t ws_size,
                              hipStream_t stream) {
    const float* x   = (const float*)d_in[0];
    const int* index = (const int*)d_in[1];
    unsigned* out_enc = (unsigned*)d_out;

    const int N = in_sizes[0] / D;  // 4194304 rows

    // 1) init output to encoded sentinel (0 < enc(any finite float))
    hipMemsetAsync(d_out, 0, (size_t)out_size * sizeof(float), stream);

    // 2) scatter-max: 64 rows/wave, 4 waves/block
    const int blocks = N / 256;
    segmax_kernel<<<blocks, 256, 0, stream>>>(x, index, out_enc);

    // 3) decode in place (vectorized: 4 elems/thread)
    const int n4 = out_size / 4;
    finalize_kernel<<<(n4 + 255) / 256, 256, 0, stream>>>(out_enc, n4);
}

// Round 2
// 209.804 us; speedup vs baseline: 2.3188x; 2.3188x over previous
//
#include <hip/hip_runtime.h>
#include <stdint.h>
#include <math.h>

#define NSEG 65536
#define D 64

// Phase 1: start[s] = lower_bound(index, N, s) for s in [0, NSEG].
// start[NSEG] == N falls out naturally (all index values < NSEG).
__global__ __launch_bounds__(256) void seg_bounds_kernel(const int* __restrict__ index,
                                                         int N, int* __restrict__ start) {
    const int s = blockIdx.x * 256 + threadIdx.x;
    if (s > NSEG) return;
    int lo = 0, hi = N;
    while (lo < hi) {
        const int mid = (lo + hi) >> 1;
        if (index[mid] < s) lo = mid + 1; else hi = mid;
    }
    start[s] = lo;
}

// Phase 2: one wave per segment. 16 lanes/row x 4 rows per iteration, float4
// per lane. Pure streaming load+fmax loop (no atomics / shfl / divergence in
// the loop; tail rows clamp to re-1, which is idempotent for max). Cross-sub
// reduce via shfl_xor(16|32), then lanes 0..15 store one coalesced 256B row.
__global__ __launch_bounds__(256) void segmax_kernel(const float* __restrict__ x,
                                                     const int* __restrict__ start,
                                                     float* __restrict__ out) {
    const int lane = threadIdx.x & 63;
    const int wave = threadIdx.x >> 6;
    const int s = blockIdx.x * 4 + wave;

    const int rs = start[s];
    const int re = start[s + 1];

    const int sub  = lane >> 4;        // row within each 4-row iteration
    const int col4 = (lane & 15) * 4;  // starting column of this lane's float4

    float4 m;
    if (rs < re) {
        m = make_float4(-INFINITY, -INFINITY, -INFINITY, -INFINITY);
        for (int r0 = rs; r0 < re; r0 += 4) {
            int r = r0 + sub;
            if (r >= re) r = re - 1;   // clamp: re-reading a row is a no-op for max
            const float4 v = *reinterpret_cast<const float4*>(x + (size_t)r * D + col4);
            m.x = fmaxf(m.x, v.x);
            m.y = fmaxf(m.y, v.y);
            m.z = fmaxf(m.z, v.z);
            m.w = fmaxf(m.w, v.w);
        }
        // reduce across the 4 sub-rows (lanes differing in bits 4..5)
        m.x = fmaxf(m.x, __shfl_xor(m.x, 16));
        m.y = fmaxf(m.y, __shfl_xor(m.y, 16));
        m.z = fmaxf(m.z, __shfl_xor(m.z, 16));
        m.w = fmaxf(m.w, __shfl_xor(m.w, 16));
        m.x = fmaxf(m.x, __shfl_xor(m.x, 32));
        m.y = fmaxf(m.y, __shfl_xor(m.y, 32));
        m.z = fmaxf(m.z, __shfl_xor(m.z, 32));
        m.w = fmaxf(m.w, __shfl_xor(m.w, 32));
    } else {
        // empty segment -> 0 (torch_scatter zero-init semantics)
        m = make_float4(0.0f, 0.0f, 0.0f, 0.0f);
    }

    if (lane < 16) {
        *reinterpret_cast<float4*>(out + (size_t)s * D + col4) = m;
    }
}

extern "C" void kernel_launch(void* const* d_in, const int* in_sizes, int n_in,
                              void* d_out, int out_size, void* d_ws, size_t ws_size,
                              hipStream_t stream) {
    const float* x   = (const float*)d_in[0];
    const int* index = (const int*)d_in[1];
    float* out       = (float*)d_out;
    int* start       = (int*)d_ws;  // NSEG+1 ints = 256 KB+4B of the ~GBs of ws

    const int N = in_sizes[0] / D;  // 4194304 rows

    seg_bounds_kernel<<<(NSEG + 1 + 255) / 256, 256, 0, stream>>>(index, N, start);
    segmax_kernel<<<NSEG / 4, 256, 0, stream>>>(x, start, out);
}

// Round 4
// 187.586 us; speedup vs baseline: 2.5935x; 1.1184x over previous
//
#include <hip/hip_runtime.h>
#include <stdint.h>
#include <math.h>

#define NSEG 65536
#define D 64

typedef float f32x4 __attribute__((ext_vector_type(4)));

// Phase 1: scan-based boundary detection over the SORTED index.
// Each thread handles 16 consecutive ints (4 x int4, coalesced). For each
// change-point index[i-1]=prev -> index[i]=cur, start[s]=i for s in (prev,cur].
// Thread covering the last element also fills start[s]=N for s>index[N-1].
__global__ __launch_bounds__(256) void seg_bounds_scan(const int* __restrict__ index,
                                                       int N, int* __restrict__ start) {
    const int t  = blockIdx.x * 256 + threadIdx.x;
    const int i0 = t * 16;
    if (i0 >= N) return;

    int prev = (i0 == 0) ? -1 : index[i0 - 1];

    int4 a0 = reinterpret_cast<const int4*>(index + i0)[0];
    int4 a1 = reinterpret_cast<const int4*>(index + i0)[1];
    int4 a2 = reinterpret_cast<const int4*>(index + i0)[2];
    int4 a3 = reinterpret_cast<const int4*>(index + i0)[3];
    int v[16] = {a0.x, a0.y, a0.z, a0.w, a1.x, a1.y, a1.z, a1.w,
                 a2.x, a2.y, a2.z, a2.w, a3.x, a3.y, a3.z, a3.w};

#pragma unroll
    for (int j = 0; j < 16; ++j) {
        const int cur = v[j];
        if (cur != prev) {
            for (int s = prev + 1; s <= cur; ++s) start[s] = i0 + j;
            prev = cur;
        }
    }
    if (i0 + 16 >= N) {  // last thread: tail segments are empty, start = N
        for (int s = prev + 1; s <= NSEG; ++s) start[s] = N;
    }
}

// Phase 2: one wave per segment. 16 lanes/row, float4/lane, nontemporal
// streaming loads. Main loop does 8 rows/iter into two independent
// accumulators (2 loads in flight/lane, no compares in the body); then one
// 4-row group; then a predicated 0-3-row tail (no redundant reads).
__global__ __launch_bounds__(256) void segmax_kernel(const float* __restrict__ x,
                                                     const int* __restrict__ start,
                                                     float* __restrict__ out) {
    const int lane = threadIdx.x & 63;
    const int wave = threadIdx.x >> 6;
    const int s = blockIdx.x * 4 + wave;

    const int rs = start[s];
    const int re = start[s + 1];

    const int sub  = lane >> 4;        // row within each 4-row group
    const int col4 = (lane & 15) * 4;  // this lane's float4 column

    f32x4 m;
    if (rs < re) {
        f32x4 m0 = {-INFINITY, -INFINITY, -INFINITY, -INFINITY};
        f32x4 m1 = m0;
        int r0 = rs;
        for (; r0 + 8 <= re; r0 += 8) {
            const f32x4 v0 = __builtin_nontemporal_load(
                reinterpret_cast<const f32x4*>(x + (size_t)(r0 + sub) * D + col4));
            const f32x4 v1 = __builtin_nontemporal_load(
                reinterpret_cast<const f32x4*>(x + (size_t)(r0 + 4 + sub) * D + col4));
            m0.x = fmaxf(m0.x, v0.x); m0.y = fmaxf(m0.y, v0.y);
            m0.z = fmaxf(m0.z, v0.z); m0.w = fmaxf(m0.w, v0.w);
            m1.x = fmaxf(m1.x, v1.x); m1.y = fmaxf(m1.y, v1.y);
            m1.z = fmaxf(m1.z, v1.z); m1.w = fmaxf(m1.w, v1.w);
        }
        if (r0 + 4 <= re) {
            const f32x4 v = __builtin_nontemporal_load(
                reinterpret_cast<const f32x4*>(x + (size_t)(r0 + sub) * D + col4));
            m0.x = fmaxf(m0.x, v.x); m0.y = fmaxf(m0.y, v.y);
            m0.z = fmaxf(m0.z, v.z); m0.w = fmaxf(m0.w, v.w);
            r0 += 4;
        }
        const int r = r0 + sub;
        if (r < re) {  // 0-3 leftover rows, exec-masked
            const f32x4 v = __builtin_nontemporal_load(
                reinterpret_cast<const f32x4*>(x + (size_t)r * D + col4));
            m1.x = fmaxf(m1.x, v.x); m1.y = fmaxf(m1.y, v.y);
            m1.z = fmaxf(m1.z, v.z); m1.w = fmaxf(m1.w, v.w);
        }
        m.x = fmaxf(m0.x, m1.x); m.y = fmaxf(m0.y, m1.y);
        m.z = fmaxf(m0.z, m1.z); m.w = fmaxf(m0.w, m1.w);
        // reduce across the 4 sub-rows (lane bits 4..5)
        m.x = fmaxf(m.x, __shfl_xor(m.x, 16));
        m.y = fmaxf(m.y, __shfl_xor(m.y, 16));
        m.z = fmaxf(m.z, __shfl_xor(m.z, 16));
        m.w = fmaxf(m.w, __shfl_xor(m.w, 16));
        m.x = fmaxf(m.x, __shfl_xor(m.x, 32));
        m.y = fmaxf(m.y, __shfl_xor(m.y, 32));
        m.z = fmaxf(m.z, __shfl_xor(m.z, 32));
        m.w = fmaxf(m.w, __shfl_xor(m.w, 32));
    } else {
        m = (f32x4){0.0f, 0.0f, 0.0f, 0.0f};  // empty segment -> 0
    }

    if (lane < 16) {
        *reinterpret_cast<f32x4*>(out + (size_t)s * D + col4) = m;
    }
}

extern "C" void kernel_launch(void* const* d_in, const int* in_sizes, int n_in,
                              void* d_out, int out_size, void* d_ws, size_t ws_size,
                              hipStream_t stream) {
    const float* x   = (const float*)d_in[0];
    const int* index = (const int*)d_in[1];
    float* out       = (float*)d_out;
    int* start       = (int*)d_ws;  // NSEG+1 ints of scratch

    const int N = in_sizes[0] / D;  // 4194304 rows

    seg_bounds_scan<<<(N / 16 + 255) / 256, 256, 0, stream>>>(index, N, start);
    segmax_kernel<<<NSEG / 4, 256, 0, stream>>>(x, start, out);
}